// Round 5
// baseline (6767.388 us; speedup 1.0000x reference)
//
#include <hip/hip_runtime.h>
#include <cstdint>
#include <cstddef>

#define TT   512
#define NWG  256
#define SLOT 65536            // floats per timestep slot in d_out
#define FINALOFF ((size_t)TT * (size_t)SLOT)

// ws layout (bytes)
#define OFF_M     0                         // M f16: 2 MiB
#define OFF_H0    2097152                   // 64*1024 f16 each
#define OFF_TH0   (OFF_H0 + 131072)
#define OFF_H1    (OFF_TH0 + 131072)
#define OFF_TH1   (OFF_H1 + 131072)
#define OFF_B0    (OFF_TH1 + 131072)        // 1024 f32
#define OFF_C1    (OFF_B0 + 4096)           // 1024 f32
#define OFF_FLAGS (OFF_C1 + 4096)           // 4 groups * 64 slots * 4 uints = 1024 uints

typedef _Float16 f16;
typedef unsigned long long ull;
typedef _Float16 v8h __attribute__((ext_vector_type(8)));
typedef float v4f __attribute__((ext_vector_type(4)));

union U2 { ull u[2]; v8h v; };

__device__ __forceinline__ void st8(void* p, ull v) {
  __hip_atomic_store((ull*)p, v, __ATOMIC_RELAXED, __HIP_MEMORY_SCOPE_AGENT);
}
__device__ __forceinline__ ull ld8(const void* p) {
  return __hip_atomic_load((const ull*)p, __ATOMIC_RELAXED, __HIP_MEMORY_SCOPE_AGENT);
}

__device__ __forceinline__ float rcpf(float x) {
#if __has_builtin(__builtin_amdgcn_rcpf)
  return __builtin_amdgcn_rcpf(x);
#else
  return 1.0f / x;
#endif
}
__device__ __forceinline__ float tanhfast(float x) {
  x = fminf(fmaxf(x, -20.0f), 20.0f);
  const float u = __expf(-2.0f * x);
  return 1.0f - 2.0f * u * rcpf(1.0f + u);
}

__global__ void k_init(unsigned int* flags) {
  flags[threadIdx.x] = 0u;  // 1024 threads cover all group flags
}

// b0[i] = bi0+bh0 ; c1[i] = Wi1.bo0 + bi1 + bh1
__global__ void k_bias(const float* __restrict__ Wi, const float* __restrict__ bi,
                       const float* __restrict__ bh, const float* __restrict__ bo,
                       float* __restrict__ b0, float* __restrict__ c1) {
  const int i = blockIdx.x * 256 + threadIdx.x;
  const float* row = Wi + 1048576 + (size_t)i * 1024;
  float s = 0.f;
  for (int k = 0; k < 1024; k += 4) {
    const float4 w = *(const float4*)&row[k];
    const float4 v = *(const float4*)&bo[k];
    s += w.x * v.x + w.y * v.y + w.z * v.z + w.w * v.w;
  }
  c1[i] = s + bi[1024 + i] + bh[1024 + i];
  b0[i] = bi[i] + bh[i];
}

// M[i][d] = sum_k Wi1[i][k] * Wo0[k][d]   (fp32 compute, f16 store)
__global__ __launch_bounds__(256) void k_gemm_M(const float* __restrict__ Wi,
                                                const float* __restrict__ Wo,
                                                f16* __restrict__ Mh) {
  const float* A = Wi + 1048576;
  const float* B = Wo;
  __shared__ float As[16][68];
  __shared__ float Bs[16][68];
  const int bi = blockIdx.x >> 4, bj = blockIdx.x & 15;
  const int i0 = bi * 64, d0 = bj * 64;
  const int ti = threadIdx.x >> 4, tj = threadIdx.x & 15;
  float acc[4][4] = {};
  for (int kc = 0; kc < 1024; kc += 16) {
    const int r = threadIdx.x >> 2, cg = (threadIdx.x & 3) << 2;
    const float4 av = *(const float4*)&A[(size_t)(i0 + r) * 1024 + kc + cg];
    As[cg + 0][r] = av.x; As[cg + 1][r] = av.y; As[cg + 2][r] = av.z; As[cg + 3][r] = av.w;
    const int c2 = threadIdx.x >> 4, dg = (threadIdx.x & 15) << 2;
    const float4 bv = *(const float4*)&B[(size_t)(kc + c2) * 1024 + d0 + dg];
    *(float4*)&Bs[c2][dg] = bv;
    __syncthreads();
#pragma unroll
    for (int kk = 0; kk < 16; ++kk) {
      float a[4], b[4];
#pragma unroll
      for (int q = 0; q < 4; ++q) { a[q] = As[kk][ti * 4 + q]; b[q] = Bs[kk][tj * 4 + q]; }
#pragma unroll
      for (int p = 0; p < 4; ++p)
#pragma unroll
        for (int q = 0; q < 4; ++q) acc[p][q] += a[p] * b[q];
    }
    __syncthreads();
  }
#pragma unroll
  for (int p = 0; p < 4; ++p)
#pragma unroll
    for (int q = 0; q < 4; ++q)
      Mh[(size_t)(i0 + ti * 4 + p) * 1024 + (size_t)(d0 + tj * 4 + q)] = (f16)acc[p][q];
}

// ---- group barrier (64 WGs per bq group), symmetric all-poll ----
__device__ __forceinline__ void gbar_arrive(unsigned int* gf, int slot, unsigned int ph) {
  asm volatile("s_waitcnt vmcnt(0)" ::: "memory");   // drain acts + prior loads
  __syncthreads();
  if (threadIdx.x == 0)
    __hip_atomic_store(&gf[slot * 4], ph, __ATOMIC_RELAXED, __HIP_MEMORY_SCOPE_AGENT);
}
__device__ __forceinline__ void gbar_wait(unsigned int* gf, unsigned int ph) {
  if (threadIdx.x < 64)
    while (__hip_atomic_load(&gf[threadIdx.x * 4], __ATOMIC_RELAXED, __HIP_MEMORY_SCOPE_AGENT) < ph)
      __builtin_amdgcn_s_sleep(1);
  __syncthreads();
  asm volatile("" ::: "memory");
}

__device__ __forceinline__ void ld_frags(const f16* base, v8h out[8]) {
  ull u0[8], u1[8];
#pragma unroll
  for (int s = 0; s < 8; ++s) { const f16* p = base + s * 32; u0[s] = ld8(p); u1[s] = ld8(p + 4); }
#pragma unroll
  for (int s = 0; s < 8; ++s) { U2 c; c.u[0] = u0[s]; c.u[1] = u1[s]; out[s] = c.v; }
}

// ---- persistent RNN loop ----
// phase A(t): h0 = z1(t) + Wh0*th1(t-1);  store h0, tanh(h0)
// window A : outs[t-1] = Wo1*h1(t-1) + bo1
// phase B(t): h1 = M*h0 + Wh1*th0 + c1;   store h1, tanh(h1)
// window B : z1(t+1) = x(t+1).Wi0^T + b0  (x read fp32 straight from d_in —
//            read-only, so the 4 bq barrier-groups share NO mutable state)
__global__ __launch_bounds__(256, 1) void k_rnn(
    const float* __restrict__ x,
    const float* __restrict__ Wi, const float* __restrict__ Wh,
    const float* __restrict__ Wo, const float* __restrict__ bo,
    char* __restrict__ ws, float* __restrict__ dout)
{
  const f16* Mh  = (const f16*)(ws + OFF_M);
  f16* h0h  = (f16*)(ws + OFF_H0);
  f16* th0h = (f16*)(ws + OFF_TH0);
  f16* h1h  = (f16*)(ws + OFF_H1);
  f16* th1h = (f16*)(ws + OFF_TH1);
  const float* b0p = (const float*)(ws + OFF_B0);
  const float* c1p = (const float*)(ws + OFF_C1);
  unsigned int* flags = (unsigned int*)(ws + OFF_FLAGS);

  const int wg = blockIdx.x;
  const int bq = wg & 3;         // batch quadrant (16 rows) — barrier group
  const int jt = wg >> 2;        // 0..63 (16 j cols) — slot within group
  const int j0 = jt * 16;
  const int tid = threadIdx.x;
  const int l = tid & 63, w = tid >> 6;
  const int lj = l & 15, lk = l >> 4;
  const int jrow = j0 + lj;
  unsigned int* gf = flags + bq * 256;

  __shared__ __align__(16) f16 WiL[16 * 1032];   // Wi0 rows j0..j0+15, f16, padded
  __shared__ float red[1024];
  __shared__ f16 trh[256];
  __shared__ f16 trh2[256];
  __shared__ float trf[256];

  // ---- weight fragments in registers ----
  v8h wWh0[8], wM[8], wWh1[8], wWo1[8];
#pragma unroll
  for (int s = 0; s < 8; ++s) {
    const int k0 = w * 256 + s * 32 + lk * 8;
    {
      const float* p = &Wh[(size_t)jrow * 1024 + k0];
      float4 a = *(const float4*)p, b = *(const float4*)(p + 4);
      wWh0[s] = (v8h){(f16)a.x,(f16)a.y,(f16)a.z,(f16)a.w,(f16)b.x,(f16)b.y,(f16)b.z,(f16)b.w};
    }
    {
      const float* p = &Wh[1048576 + (size_t)jrow * 1024 + k0];
      float4 a = *(const float4*)p, b = *(const float4*)(p + 4);
      wWh1[s] = (v8h){(f16)a.x,(f16)a.y,(f16)a.z,(f16)a.w,(f16)b.x,(f16)b.y,(f16)b.z,(f16)b.w};
    }
    {
      const float* p = &Wo[1048576 + (size_t)jrow * 1024 + k0];
      float4 a = *(const float4*)p, b = *(const float4*)(p + 4);
      wWo1[s] = (v8h){(f16)a.x,(f16)a.y,(f16)a.z,(f16)a.w,(f16)b.x,(f16)b.y,(f16)b.z,(f16)b.w};
    }
    wM[s] = *(const v8h*)&Mh[(size_t)jrow * 1024 + k0];
  }
  // Wi0 row tile -> LDS (f16)
  for (int u = tid; u < 4096; u += 256) {
    const int rr = u >> 8, c4 = (u & 255) << 2;
    const float4 v = *(const float4*)&Wi[(size_t)(j0 + rr) * 1024 + c4];
    f16* dst = &WiL[rr * 1032 + c4];
    dst[0] = (f16)v.x; dst[1] = (f16)v.y; dst[2] = (f16)v.z; dst[3] = (f16)v.w;
  }
  const int rj = tid & 15;
  const float b0v = b0p[j0 + rj];
  const float c1v = c1p[j0 + rj];
  const float bo1v = bo[1024 + j0 + rj];
  __syncthreads();

  const size_t actbase = (size_t)(bq * 16 + lj) * 1024 + (size_t)(w * 256 + lk * 8);
  const int redw = w * 256 + lk * 64 + lj;   // + q*16 per element

  // z1 tile for one timestep: x fp32 from d_in (read-only), convert, MFMA
  auto z1_dot = [&](const float* xt) -> float {
    v4f acc = {0.f, 0.f, 0.f, 0.f};
#pragma unroll
    for (int s = 0; s < 8; ++s) {
      const float* p = xt + actbase + s * 32;
      const float4 a = *(const float4*)p;
      const float4 b = *(const float4*)(p + 4);
      const v8h af = {(f16)a.x,(f16)a.y,(f16)a.z,(f16)a.w,
                      (f16)b.x,(f16)b.y,(f16)b.z,(f16)b.w};
      const v8h bf = *(const v8h*)&WiL[lj * 1032 + w * 256 + s * 32 + lk * 8];
      acc = __builtin_amdgcn_mfma_f32_16x16x32_f16(af, bf, acc, 0, 0, 0);
    }
#pragma unroll
    for (int q = 0; q < 4; ++q) red[redw + q * 16] = acc[q];
    __syncthreads();
    const float r = red[tid] + red[256 + tid] + red[512 + tid] + red[768 + tid] + b0v;
    __syncthreads();
    return r;
  };

  float zc = z1_dot(x);   // z1(0)
  unsigned int ph = 0;

  for (int t = 0; t <= TT; ++t) {
    const bool A = (t < TT), R = (t > 0);
    v8h thf[8], hrf[8];

    if (R) {
      ld_frags(th1h + actbase, thf);   // tanh(h1(t-1)) — critical
      ld_frags(h1h + actbase, hrf);    // raw h1(t-1) — for out-GEMM
    }

    // ---------- phase A: h0 = z1(t) + Wh0 * th1 ----------
    {
      v4f acc = {0.f, 0.f, 0.f, 0.f};
      if (R) {
#pragma unroll
        for (int s = 0; s < 8; ++s)
          acc = __builtin_amdgcn_mfma_f32_16x16x32_f16(thf[s], wWh0[s], acc, 0, 0, 0);
      }
#pragma unroll
      for (int q = 0; q < 4; ++q) red[redw + q * 16] = acc[q];
      __syncthreads();
      if (A) {
        const float h0 = red[tid] + red[256 + tid] + red[512 + tid] + red[768 + tid] + zc;
        trh[tid] = (f16)h0;
        trh2[tid] = (f16)tanhfast(h0);
      }
      __syncthreads();
      if (A) {
        if (tid < 64) {
          st8(&h0h[(size_t)(bq * 16 + (tid >> 2)) * 1024 + j0 + (tid & 3) * 4],
              ((const ull*)trh)[tid]);
        } else if (tid < 128) {
          const int u = tid - 64;
          st8(&th0h[(size_t)(bq * 16 + (u >> 2)) * 1024 + j0 + (u & 3) * 4],
              ((const ull*)trh2)[u]);
        }
      }
    }
    gbar_arrive(gf, jt, ++ph);

    // ---------- window A: outs[t-1] = Wo1*h1 + bo1 ----------
    if (R) {
      v4f a2 = {0.f, 0.f, 0.f, 0.f};
#pragma unroll
      for (int s = 0; s < 8; ++s)
        a2 = __builtin_amdgcn_mfma_f32_16x16x32_f16(hrf[s], wWo1[s], a2, 0, 0, 0);
#pragma unroll
      for (int q = 0; q < 4; ++q) red[redw + q * 16] = a2[q];
      __syncthreads();
      trf[tid] = red[tid] + red[256 + tid] + red[512 + tid] + red[768 + tid] + bo1v;
      __syncthreads();
      if (tid < 128)
        st8(&dout[(size_t)(t - 1) * SLOT + (size_t)(bq * 16 + (tid >> 3)) * 1024 + j0 + (tid & 7) * 2],
            ((const ull*)trf)[tid]);
    }
    gbar_wait(gf, ph);

    // ---------- phase B: h1 = M*h0 + Wh1*th0 + c1 ----------
    if (A) {
      v8h g0f[8], t0f[8];
      ld_frags(h0h + actbase, g0f);
      ld_frags(th0h + actbase, t0f);
      v4f aM = {0.f, 0.f, 0.f, 0.f}, aW = {0.f, 0.f, 0.f, 0.f};
#pragma unroll
      for (int s = 0; s < 8; ++s) {
        aM = __builtin_amdgcn_mfma_f32_16x16x32_f16(g0f[s], wM[s], aM, 0, 0, 0);
        aW = __builtin_amdgcn_mfma_f32_16x16x32_f16(t0f[s], wWh1[s], aW, 0, 0, 0);
      }
#pragma unroll
      for (int q = 0; q < 4; ++q) red[redw + q * 16] = aM[q] + aW[q];
      __syncthreads();
      const float h1 = red[tid] + red[256 + tid] + red[512 + tid] + red[768 + tid] + c1v;
      const bool last = (t == TT - 1);
      trh[tid] = (f16)h1;
      const float th1v = tanhfast(h1);
      trh2[tid] = (f16)th1v;
      if (last) trf[tid] = th1v;
      __syncthreads();
      if (tid < 64) {
        st8(&h1h[(size_t)(bq * 16 + (tid >> 2)) * 1024 + j0 + (tid & 3) * 4],
            ((const ull*)trh)[tid]);
      } else if (tid < 128) {
        const int u = tid - 64;
        st8(&th1h[(size_t)(bq * 16 + (u >> 2)) * 1024 + j0 + (u & 3) * 4],
            ((const ull*)trh2)[u]);
      }
      if (last && tid < 128)
        st8(&dout[FINALOFF + (size_t)(bq * 16 + (tid >> 3)) * 1024 + j0 + (tid & 7) * 2],
            ((const ull*)trf)[tid]);
      gbar_arrive(gf, jt, ++ph);

      // ---------- window B: z1(t+1) ----------
      float zn = zc;
      if (t + 1 < TT)
        zn = z1_dot(x + (size_t)(t + 1) * SLOT);
      gbar_wait(gf, ph);
      zc = zn;
    }
  }
}

extern "C" void kernel_launch(void* const* d_in, const int* in_sizes, int n_in,
                              void* d_out, int out_size, void* d_ws, size_t ws_size,
                              hipStream_t stream) {
  (void)in_sizes; (void)n_in; (void)out_size; (void)ws_size;
  const float* x  = (const float*)d_in[0];
  const float* Wi = (const float*)d_in[1];
  const float* bi = (const float*)d_in[2];
  const float* Wh = (const float*)d_in[3];
  const float* bh = (const float*)d_in[4];
  const float* Wo = (const float*)d_in[5];
  const float* bo = (const float*)d_in[6];
  char* ws = (char*)d_ws;
  float* out = (float*)d_out;

  k_init<<<1, 1024, 0, stream>>>((unsigned int*)(ws + OFF_FLAGS));
  k_bias<<<4, 256, 0, stream>>>(Wi, bi, bh, bo, (float*)(ws + OFF_B0), (float*)(ws + OFF_C1));
  k_gemm_M<<<256, 256, 0, stream>>>(Wi, Wo, (f16*)(ws + OFF_M));
  k_rnn<<<NWG, 256, 0, stream>>>(x, Wi, Wh, Wo, bo, ws, out);
}

// Round 6
// 6437.260 us; speedup vs baseline: 1.0513x; 1.0513x over previous
//
#include <hip/hip_runtime.h>
#include <cstdint>
#include <cstddef>

#define TT   512
#define NWG  512              // 256 compute + 256 aux
#define SLOT 65536            // floats per timestep slot in d_out
#define FINALOFF ((size_t)TT * (size_t)SLOT)

// ws layout (bytes)
#define OFF_M     0                         // M f16: 2 MiB
#define OFF_H0    2097152                   // 64*1024 f16 each (128 KiB)
#define OFF_TH0   (OFF_H0 + 131072)
#define OFF_H1A   (OFF_TH0 + 131072)
#define OFF_H1B   (OFF_H1A + 131072)
#define OFF_TH1   (OFF_H1B + 131072)
#define OFF_Z0    (OFF_TH1 + 131072)
#define OFF_Z1    (OFF_Z0 + 131072)
#define OFF_B0    (OFF_Z1 + 131072)         // 1024 f32
#define OFF_C1    (OFF_B0 + 4096)           // 1024 f32
#define OFF_CF    (OFF_C1 + 4096)           // compute flags: 4 grp * 64 slot * 16B
#define OFF_AF    (OFF_CF + 4096)           // aux flags: same

typedef _Float16 f16;
typedef unsigned long long ull;
typedef _Float16 v8h __attribute__((ext_vector_type(8)));
typedef float v4f __attribute__((ext_vector_type(4)));

union U2 { ull u[2]; v8h v; };

__device__ __forceinline__ void st2(void* p, f16 v) {
  __hip_atomic_store((unsigned short*)p, __builtin_bit_cast(unsigned short, v),
                     __ATOMIC_RELAXED, __HIP_MEMORY_SCOPE_AGENT);
}
__device__ __forceinline__ f16 ld2(const void* p) {
  unsigned short u = __hip_atomic_load((const unsigned short*)p,
                                       __ATOMIC_RELAXED, __HIP_MEMORY_SCOPE_AGENT);
  return __builtin_bit_cast(f16, u);
}
__device__ __forceinline__ ull ld8(const void* p) {
  return __hip_atomic_load((const ull*)p, __ATOMIC_RELAXED, __HIP_MEMORY_SCOPE_AGENT);
}

__device__ __forceinline__ float rcpf(float x) {
#if __has_builtin(__builtin_amdgcn_rcpf)
  return __builtin_amdgcn_rcpf(x);
#else
  return 1.0f / x;
#endif
}
__device__ __forceinline__ float tanhfast(float x) {
  x = fminf(fmaxf(x, -20.0f), 20.0f);
  const float u = __expf(-2.0f * x);
  return 1.0f - 2.0f * u * rcpf(1.0f + u);
}

__global__ void k_init(unsigned int* flags) {
  flags[blockIdx.x * 1024 + threadIdx.x] = 0u;  // 2048 uints = CF + AF
}

// b0[i] = bi0+bh0 ; c1[i] = Wi1.bo0 + bi1 + bh1
__global__ void k_bias(const float* __restrict__ Wi, const float* __restrict__ bi,
                       const float* __restrict__ bh, const float* __restrict__ bo,
                       float* __restrict__ b0, float* __restrict__ c1) {
  const int i = blockIdx.x * 256 + threadIdx.x;
  const float* row = Wi + 1048576 + (size_t)i * 1024;
  float s = 0.f;
  for (int k = 0; k < 1024; k += 4) {
    const float4 w = *(const float4*)&row[k];
    const float4 v = *(const float4*)&bo[k];
    s += w.x * v.x + w.y * v.y + w.z * v.z + w.w * v.w;
  }
  c1[i] = s + bi[1024 + i] + bh[1024 + i];
  b0[i] = bi[i] + bh[i];
}

// M[i][d] = sum_k Wi1[i][k] * Wo0[k][d]   (fp32 compute, f16 store)
__global__ __launch_bounds__(256) void k_gemm_M(const float* __restrict__ Wi,
                                                const float* __restrict__ Wo,
                                                f16* __restrict__ Mh) {
  const float* A = Wi + 1048576;
  const float* B = Wo;
  __shared__ float As[16][68];
  __shared__ float Bs[16][68];
  const int bi = blockIdx.x >> 4, bj = blockIdx.x & 15;
  const int i0 = bi * 64, d0 = bj * 64;
  const int ti = threadIdx.x >> 4, tj = threadIdx.x & 15;
  float acc[4][4] = {};
  for (int kc = 0; kc < 1024; kc += 16) {
    const int r = threadIdx.x >> 2, cg = (threadIdx.x & 3) << 2;
    const float4 av = *(const float4*)&A[(size_t)(i0 + r) * 1024 + kc + cg];
    As[cg + 0][r] = av.x; As[cg + 1][r] = av.y; As[cg + 2][r] = av.z; As[cg + 3][r] = av.w;
    const int c2 = threadIdx.x >> 4, dg = (threadIdx.x & 15) << 2;
    const float4 bv = *(const float4*)&B[(size_t)(kc + c2) * 1024 + d0 + dg];
    *(float4*)&Bs[c2][dg] = bv;
    __syncthreads();
#pragma unroll
    for (int kk = 0; kk < 16; ++kk) {
      float a[4], b[4];
#pragma unroll
      for (int q = 0; q < 4; ++q) { a[q] = As[kk][ti * 4 + q]; b[q] = Bs[kk][tj * 4 + q]; }
#pragma unroll
      for (int p = 0; p < 4; ++p)
#pragma unroll
        for (int q = 0; q < 4; ++q) acc[p][q] += a[p] * b[q];
    }
    __syncthreads();
  }
#pragma unroll
  for (int p = 0; p < 4; ++p)
#pragma unroll
    for (int q = 0; q < 4; ++q)
      Mh[(size_t)(i0 + ti * 4 + p) * 1024 + (size_t)(d0 + tj * 4 + q)] = (f16)acc[p][q];
}

__device__ __forceinline__ void ld_frags(const f16* base, v8h out[8]) {
  ull u0[8], u1[8];
#pragma unroll
  for (int s = 0; s < 8; ++s) { const f16* p = base + s * 32; u0[s] = ld8(p); u1[s] = ld8(p + 4); }
#pragma unroll
  for (int s = 0; s < 8; ++s) { U2 c; c.u[0] = u0[s]; c.u[1] = u1[s]; out[s] = c.v; }
}

// ---- persistent RNN: 256 compute WGs + 256 aux WGs (2 per CU) ----
// compute (bq,jt):  A(t): h0 = z1(t) + Wh0*th1(t-1)   -> h0, th0
//                   B(t): h1 = M*h0 + Wh1*th0 + c1    -> h1buf[t&1], th1
// aux (bq,jt):      it 0: z1(0), z1(1);  it i>=1: outs(i-1) = Wo1*h1(i-1)+bo1 ; z1(i+1)
// sync: compute pre-A(t) needs group C-flags >= 2t AND group aux flags >= max(t,1);
//       compute pre-B(t) needs C-flags >= 2t+1; aux it i needs C-flags >= 2i.
__global__ __launch_bounds__(256, 2) void k_rnn(
    const float* __restrict__ x,
    const float* __restrict__ Wi, const float* __restrict__ Wh,
    const float* __restrict__ Wo, const float* __restrict__ bo,
    char* __restrict__ ws, float* __restrict__ dout)
{
  const f16* Mh  = (const f16*)(ws + OFF_M);
  f16* h0h  = (f16*)(ws + OFF_H0);
  f16* th0h = (f16*)(ws + OFF_TH0);
  f16* h1b[2] = { (f16*)(ws + OFF_H1A), (f16*)(ws + OFF_H1B) };
  f16* th1h = (f16*)(ws + OFF_TH1);
  f16* zb[2] = { (f16*)(ws + OFF_Z0), (f16*)(ws + OFF_Z1) };
  const float* b0p = (const float*)(ws + OFF_B0);
  const float* c1p = (const float*)(ws + OFF_C1);

  const int wg = blockIdx.x;
  const bool is_aux = (wg >= 256);
  const int p = is_aux ? (wg - 256) : wg;
  const int bq = p & 3;          // batch quadrant (16 rows) — barrier group
  const int jt = p >> 2;         // 0..63 (16 j cols) — slot within group
  const int j0 = jt * 16;
  const int tid = threadIdx.x;
  const int l = tid & 63, w = tid >> 6;
  const int lj = l & 15, lk = l >> 4;
  const int jrow = j0 + lj;
  const int rb = tid >> 4, rj = tid & 15;   // reducer (batch-in-16, j-in-16)

  unsigned int* gfC = (unsigned int*)(ws + OFF_CF) + bq * 256;
  unsigned int* gfA = (unsigned int*)(ws + OFF_AF) + bq * 256;

  __shared__ __align__(16) f16 WiL[16 * 1032];
  __shared__ float red[1024];

  const size_t actbase = (size_t)(bq * 16 + lj) * 1024 + (size_t)(w * 256 + lk * 8);
  const int redw = w * 256 + lk * 64 + lj;
  const size_t rdst = (size_t)(bq * 16 + rb) * 1024 + (size_t)(j0 + rj);

  if (!is_aux) {
    // ================= COMPUTE =================
    v8h wWh0[8], wM[8], wWh1[8];
#pragma unroll
    for (int s = 0; s < 8; ++s) {
      const int k0 = w * 256 + s * 32 + lk * 8;
      {
        const float* pp = &Wh[(size_t)jrow * 1024 + k0];
        float4 a = *(const float4*)pp, b = *(const float4*)(pp + 4);
        wWh0[s] = (v8h){(f16)a.x,(f16)a.y,(f16)a.z,(f16)a.w,(f16)b.x,(f16)b.y,(f16)b.z,(f16)b.w};
      }
      {
        const float* pp = &Wh[1048576 + (size_t)jrow * 1024 + k0];
        float4 a = *(const float4*)pp, b = *(const float4*)(pp + 4);
        wWh1[s] = (v8h){(f16)a.x,(f16)a.y,(f16)a.z,(f16)a.w,(f16)b.x,(f16)b.y,(f16)b.z,(f16)b.w};
      }
      wM[s] = *(const v8h*)&Mh[(size_t)jrow * 1024 + k0];
    }
    const float c1v = c1p[j0 + rj];

    for (int t = 0; t < TT; ++t) {
      const unsigned int cthA = 2u * t;
      const unsigned int athA = (t == 0) ? 1u : (unsigned int)t;
      if (tid < 64) {
        while (__hip_atomic_load(&gfC[tid * 4], __ATOMIC_RELAXED, __HIP_MEMORY_SCOPE_AGENT) < cthA)
          __builtin_amdgcn_s_sleep(1);
      } else if (tid < 128) {
        while (__hip_atomic_load(&gfA[(tid - 64) * 4], __ATOMIC_RELAXED, __HIP_MEMORY_SCOPE_AGENT) < athA)
          __builtin_amdgcn_s_sleep(1);
      }
      __syncthreads();

      // ---- phase A ----
      const f16 zv = ld2(&zb[t & 1][rdst]);     // prefetch z1(t)
      v4f acc = {0.f, 0.f, 0.f, 0.f};
      if (t > 0) {
        v8h thf[8];
        ld_frags(th1h + actbase, thf);
#pragma unroll
        for (int s = 0; s < 8; ++s)
          acc = __builtin_amdgcn_mfma_f32_16x16x32_f16(thf[s], wWh0[s], acc, 0, 0, 0);
      }
#pragma unroll
      for (int q = 0; q < 4; ++q) red[redw + q * 16] = acc[q];
      __syncthreads();
      const float h0 = red[tid] + red[256 + tid] + red[512 + tid] + red[768 + tid] + (float)zv;
      st2(&h0h[rdst], (f16)h0);
      st2(&th0h[rdst], (f16)tanhfast(h0));
      asm volatile("s_waitcnt vmcnt(0)" ::: "memory");
      __syncthreads();
      if (tid == 0)
        __hip_atomic_store(&gfC[jt * 4], 2u * t + 1u, __ATOMIC_RELAXED, __HIP_MEMORY_SCOPE_AGENT);

      // ---- wait B ----
      if (tid < 64) {
        while (__hip_atomic_load(&gfC[tid * 4], __ATOMIC_RELAXED, __HIP_MEMORY_SCOPE_AGENT) < 2u * t + 1u)
          __builtin_amdgcn_s_sleep(1);
      }
      __syncthreads();

      // ---- phase B ----
      v8h g0f[8], t0f[8];
      ld_frags(h0h + actbase, g0f);
      ld_frags(th0h + actbase, t0f);
      v4f aM = {0.f, 0.f, 0.f, 0.f}, aW = {0.f, 0.f, 0.f, 0.f};
#pragma unroll
      for (int s = 0; s < 8; ++s) {
        aM = __builtin_amdgcn_mfma_f32_16x16x32_f16(g0f[s], wM[s], aM, 0, 0, 0);
        aW = __builtin_amdgcn_mfma_f32_16x16x32_f16(t0f[s], wWh1[s], aW, 0, 0, 0);
      }
#pragma unroll
      for (int q = 0; q < 4; ++q) red[redw + q * 16] = aM[q] + aW[q];
      __syncthreads();
      const float h1 = red[tid] + red[256 + tid] + red[512 + tid] + red[768 + tid] + c1v;
      const float th1v = tanhfast(h1);
      st2(&h1b[t & 1][rdst], (f16)h1);
      st2(&th1h[rdst], (f16)th1v);
      if (t == TT - 1) dout[FINALOFF + rdst] = th1v;
      asm volatile("s_waitcnt vmcnt(0)" ::: "memory");
      __syncthreads();
      if (tid == 0)
        __hip_atomic_store(&gfC[jt * 4], 2u * t + 2u, __ATOMIC_RELAXED, __HIP_MEMORY_SCOPE_AGENT);
    }
  } else {
    // ================= AUX =================
    v8h wWo1[8];
#pragma unroll
    for (int s = 0; s < 8; ++s) {
      const int k0 = w * 256 + s * 32 + lk * 8;
      const float* pp = &Wo[1048576 + (size_t)jrow * 1024 + k0];
      float4 a = *(const float4*)pp, b = *(const float4*)(pp + 4);
      wWo1[s] = (v8h){(f16)a.x,(f16)a.y,(f16)a.z,(f16)a.w,(f16)b.x,(f16)b.y,(f16)b.z,(f16)b.w};
    }
    // Wi0 row tile -> LDS (f16)
    for (int u = tid; u < 4096; u += 256) {
      const int rr = u >> 8, c4 = (u & 255) << 2;
      const float4 v = *(const float4*)&Wi[(size_t)(j0 + rr) * 1024 + c4];
      f16* dst = &WiL[rr * 1032 + c4];
      dst[0] = (f16)v.x; dst[1] = (f16)v.y; dst[2] = (f16)v.z; dst[3] = (f16)v.w;
    }
    const float b0v = b0p[j0 + rj];
    const float bo1v = bo[1024 + j0 + rj];
    __syncthreads();

    auto z1c = [&](const float* xt, f16* zdst) {
      __syncthreads();                       // red reuse guard
      v4f acc = {0.f, 0.f, 0.f, 0.f};
#pragma unroll
      for (int s = 0; s < 8; ++s) {
        const float* pp = xt + actbase + s * 32;
        const float4 a = *(const float4*)pp;
        const float4 b = *(const float4*)(pp + 4);
        const v8h af = {(f16)a.x,(f16)a.y,(f16)a.z,(f16)a.w,
                        (f16)b.x,(f16)b.y,(f16)b.z,(f16)b.w};
        const v8h bf = *(const v8h*)&WiL[lj * 1032 + w * 256 + s * 32 + lk * 8];
        acc = __builtin_amdgcn_mfma_f32_16x16x32_f16(af, bf, acc, 0, 0, 0);
      }
#pragma unroll
      for (int q = 0; q < 4; ++q) red[redw + q * 16] = acc[q];
      __syncthreads();
      const float r = red[tid] + red[256 + tid] + red[512 + tid] + red[768 + tid] + b0v;
      st2(&zdst[rdst], (f16)r);
    };

    // iteration 0: z1(0), z1(1)
    z1c(x, zb[0]);
    z1c(x + SLOT, zb[1]);
    asm volatile("s_waitcnt vmcnt(0)" ::: "memory");
    __syncthreads();
    if (tid == 0)
      __hip_atomic_store(&gfA[jt * 4], 1u, __ATOMIC_RELAXED, __HIP_MEMORY_SCOPE_AGENT);

    for (int i = 1; i <= TT; ++i) {
      if (tid < 64) {
        while (__hip_atomic_load(&gfC[tid * 4], __ATOMIC_RELAXED, __HIP_MEMORY_SCOPE_AGENT) < 2u * i)
          __builtin_amdgcn_s_sleep(1);
      }
      __syncthreads();

      // outs(i-1) = Wo1 * h1(i-1) + bo1
      v8h hrf[8];
      ld_frags(h1b[(i - 1) & 1] + actbase, hrf);
      v4f a2 = {0.f, 0.f, 0.f, 0.f};
#pragma unroll
      for (int s = 0; s < 8; ++s)
        a2 = __builtin_amdgcn_mfma_f32_16x16x32_f16(hrf[s], wWo1[s], a2, 0, 0, 0);
#pragma unroll
      for (int q = 0; q < 4; ++q) red[redw + q * 16] = a2[q];
      __syncthreads();
      const float s1 = red[tid] + red[256 + tid] + red[512 + tid] + red[768 + tid] + bo1v;
      dout[(size_t)(i - 1) * SLOT + rdst] = s1;

      if (i + 1 < TT) z1c(x + (size_t)(i + 1) * SLOT, zb[(i + 1) & 1]);

      asm volatile("s_waitcnt vmcnt(0)" ::: "memory");
      __syncthreads();
      if (tid == 0)
        __hip_atomic_store(&gfA[jt * 4], (unsigned int)(i + 1), __ATOMIC_RELAXED, __HIP_MEMORY_SCOPE_AGENT);
    }
  }
}

extern "C" void kernel_launch(void* const* d_in, const int* in_sizes, int n_in,
                              void* d_out, int out_size, void* d_ws, size_t ws_size,
                              hipStream_t stream) {
  (void)in_sizes; (void)n_in; (void)out_size; (void)ws_size;
  const float* x  = (const float*)d_in[0];
  const float* Wi = (const float*)d_in[1];
  const float* bi = (const float*)d_in[2];
  const float* Wh = (const float*)d_in[3];
  const float* bh = (const float*)d_in[4];
  const float* Wo = (const float*)d_in[5];
  const float* bo = (const float*)d_in[6];
  char* ws = (char*)d_ws;
  float* out = (float*)d_out;

  k_init<<<2, 1024, 0, stream>>>((unsigned int*)(ws + OFF_CF));
  k_bias<<<4, 256, 0, stream>>>(Wi, bi, bh, bo, (float*)(ws + OFF_B0), (float*)(ws + OFF_C1));
  k_gemm_M<<<256, 256, 0, stream>>>(Wi, Wo, (f16*)(ws + OFF_M));
  k_rnn<<<NWG, 256, 0, stream>>>(x, Wi, Wh, Wo, bo, ws, out);
}